// Round 1
// 686.936 us; speedup vs baseline: 1.0922x; 1.0922x over previous
//
#include <hip/hip_runtime.h>

#define B_   8
#define D_   256
#define T_   4096
#define NQ_  8
#define K_   1024

#define IDX_OFF  ((size_t)B_ * T_ * D_)             // 8388608
#define LOSS_OFF (IDX_OFF + (size_t)NQ_ * B_ * T_)  // 8650752

// ---- workspace layout (bytes) ----
#define XT_OFF   0ull                      // float xT[32768][256] (32 MB)
#define CB16_OFF 33554432ull               // fp16 codebook in MFMA A-frag order (4 MB)
#define CN_OFF   37748736ull               // float cnorm[8192]
#define LB_OFF   37781504ull               // double lossbuf[8]

#define RST 260                            // res row stride (floats); swizzle handles banks

typedef _Float16 half8 __attribute__((ext_vector_type(8)));   // 4 VGPR MFMA frag
typedef _Float16 h2f   __attribute__((ext_vector_type(2)));
typedef float   f32x16 __attribute__((ext_vector_type(16)));  // MFMA C/D

__device__ __forceinline__ ushort f2h(float f) {
  return __builtin_bit_cast(ushort, (_Float16)f);
}
__device__ __forceinline__ int swz(int blk) { return blk ^ ((blk >> 2) & 3); } // 8-dim block swizzle

// packed score: low 10 mantissa bits replaced by code -> branch-free sorted-top-3 via min/max net
__device__ __forceinline__ float packsc(float sc, uint code) {
  return __builtin_bit_cast(float, (__builtin_bit_cast(uint, sc) & ~1023u) | code);
}
__device__ __forceinline__ void ins3(float& v1, float& v2, float& v3, float f) {
  const float a1 = fminf(v1, f), b1 = fmaxf(v1, f);
  v1 = a1;
  const float a2 = fminf(v2, b1), b2 = fmaxf(v2, b1);
  v2 = a2;
  v3 = fminf(v3, b2);
}

// ---- prep 1: x [B,D,T] -> xT f32 [row=b*T+t][d] ----
__global__ void prep_xT(const float* __restrict__ x, float* __restrict__ xT) {
  __shared__ float tile[64][65];
  const int bidx = blockIdx.x;                 // 8 b * 4 dchunk * 64 tchunk
  const int b = bidx >> 8, dc = (bidx >> 6) & 3, tc = bidx & 63;
  const int d0 = dc * 64, t0 = tc * 64;
  const int tid = threadIdx.x;
  {
    const int tt = tid & 63, dg = tid >> 6;
    for (int i = 0; i < 16; ++i) {
      const int d = dg * 16 + i;
      tile[d][tt] = x[((size_t)(b * D_ + d0 + d)) * T_ + t0 + tt];
    }
  }
  __syncthreads();
  {
    const int dw = tid & 63, tg = tid >> 6;
    for (int i = 0; i < 16; ++i) {
      const int t = tg * 16 + i;
      xT[((size_t)b * T_ + t0 + t) * D_ + d0 + dw] = tile[dw][t];
    }
  }
}

// ---- prep 2: cb f32 -> fp16 MFMA A-frag order + f64-accurate cnorm (f32 out) ----
// layout: cb16[stage][tile(code>>5)][ks(k>>4)][lane][8]; lane = ((k>>3)&1)*32 + (code&31), j=k&7
__global__ void prep_cb16(const float* __restrict__ cb, ushort* __restrict__ cb16,
                          float* __restrict__ cnorm) {
  const int tid = threadIdx.x, w = tid >> 6, l = tid & 63;
  const int code = blockIdx.x * 4 + w;         // grid 2048
  const int s = code >> 10, ci = code & 1023, tile = ci >> 5, n = ci & 31;
  const float* row = cb + (size_t)code * D_;
  const float4 v = *(const float4*)(row + l * 4);
  double nrm = (double)v.x * v.x + (double)v.y * v.y + (double)v.z * v.z + (double)v.w * v.w;
  ushort4 p;
  p.x = f2h(v.x); p.y = f2h(v.y); p.z = f2h(v.z); p.w = f2h(v.w);
  const int ks = l >> 2, lf = ((l >> 1) & 1) * 32 + n, j0 = (l & 1) * 4;
  const size_t off = (((size_t)s * 32 + tile) * 16 + ks) * 512 + (size_t)lf * 8 + j0;
  *(ushort4*)(cb16 + off) = p;
#pragma unroll
  for (int m = 1; m <= 32; m <<= 1) nrm += __shfl_xor(nrm, m);
  if (l == 0) cnorm[code] = (float)nrm;
}

// ---- main: 1024 blocks x 256 thr; block = 32 rows; wave w = codes w*256..+255 (8 tiles) ----
// LDS: resHi only (~35 KB) -> 4 blocks/CU resident (entire grid). Residual low part lives in
// 32 phase-3-private VGPRs (stage-invariant thread->dim mapping), numerics unchanged.
__attribute__((amdgpu_waves_per_eu(4, 4)))
__global__ __launch_bounds__(256)
void rvq_main(const float* __restrict__ cb, const float* __restrict__ xT,
              const ushort* __restrict__ cb16, const float* __restrict__ cnorm,
              float* __restrict__ out, double* __restrict__ lossbuf) {
  __shared__ __align__(16) float resHi[32 * RST];   // 33.3 KB
  __shared__ __align__(16) float candm[32][12];     // packed score|code, 1.5 KB

  const int tid = threadIdx.x;
  const int w = tid >> 6, l = tid & 63, n5 = l & 31, h = l >> 5;
  const size_t row0 = (size_t)blockIdx.x * 32;
  const int rowL = tid >> 3;            // phase-3 row  (== w*8 + (l>>3))
  const int dq = tid & 7;               // phase-3 dim-octant (32 dims)

  float lo[4][8];                       // residual low part (double-single), register-resident

  // ---- init: residual pair = (x, 0) ----
  {
#pragma unroll
    for (int cc = 0; cc < 4; ++cc) {
      const int blk = dq * 4 + cc;
      const float* xp = xT + (row0 + rowL) * D_ + blk * 8;
      const float4 x0 = *(const float4*)xp, x1 = *(const float4*)(xp + 4);
      const int po = rowL * RST + swz(blk) * 8;
      *(float4*)(resHi + po) = x0; *(float4*)(resHi + po + 4) = x1;
#pragma unroll
      for (int j = 0; j < 8; ++j) lo[cc][j] = 0.0f;
    }
  }
  __syncthreads();

  for (int s = 0; s < NQ_; ++s) {
    // ===== B fragments: residual fp16 (pkrtz), n = n5, k = ks*16 + h*8 + j =====
    half8 b[16];
#pragma unroll
    for (int ks = 0; ks < 16; ++ks) {
      const int po = n5 * RST + swz(ks * 2 + h) * 8;
      const float4 f0 = *(const float4*)(resHi + po);
      const float4 f1 = *(const float4*)(resHi + po + 4);
      union { half8 h8; uint u[4]; } bu;
      bu.u[0] = __builtin_bit_cast(uint, __builtin_amdgcn_cvt_pkrtz(f0.x, f0.y));
      bu.u[1] = __builtin_bit_cast(uint, __builtin_amdgcn_cvt_pkrtz(f0.z, f0.w));
      bu.u[2] = __builtin_bit_cast(uint, __builtin_amdgcn_cvt_pkrtz(f1.x, f1.y));
      bu.u[3] = __builtin_bit_cast(uint, __builtin_amdgcn_cvt_pkrtz(f1.z, f1.w));
      b[ks] = bu.h8;
    }

    // ===== K-loop: 8 tiles x 16 MFMAs; per-lane branch-free top-3 over own x-row =====
    float v1 = 3e38f, v2 = 3e38f, v3 = 3e38f;
    for (int tt = 0; tt < 8; ++tt) {
      const int t = w * 8 + tt;
      const uint4* ap = (const uint4*)(cb16 + ((size_t)(s * 32 + t) * 16) * 512) + l;
      f32x16 acc;
#pragma unroll
      for (int r = 0; r < 16; ++r) acc[r] = 0.0f;
#pragma unroll
      for (int ks = 0; ks < 16; ++ks) {
        const uint4 av = ap[(size_t)ks * 64];
        acc = __builtin_amdgcn_mfma_f32_32x32x16_f16(__builtin_bit_cast(half8, av), b[ks], acc, 0, 0, 0);
      }
      const float* cnb = cnorm + s * K_ + t * 32 + h * 4;
      const uint cbase = (uint)(t * 32 + 4 * h);
#pragma unroll
      for (int q = 0; q < 4; ++q) {                      // quarter-split keeps cna regs low
        const float4 cq = *(const float4*)(cnb + q * 8);
        const float cna[4] = {cq.x, cq.y, cq.z, cq.w};
#pragma unroll
        for (int rr = 0; rr < 4; ++rr) {
          const int r = q * 4 + rr;
          const float sc = cna[rr] - 2.0f * acc[r];
          const uint code = cbase + (uint)(8 * q + rr);  // == t*32 + (r&3) + 8*(r>>2) + 4*h
          ins3(v1, v2, v3, packsc(sc, code));
        }
      }
    }
    // merge h-halves (lane l <-> l^32, same x-row, disjoint codes)
    {
      const float o1 = __shfl_xor(v1, 32), o2 = __shfl_xor(v2, 32), o3 = __shfl_xor(v3, 32);
      ins3(v1, v2, v3, o1);
      ins3(v1, v2, v3, o2);
      ins3(v1, v2, v3, o3);
    }
    if (h == 0) {
      candm[n5][w * 3 + 0] = v1;
      candm[n5][w * 3 + 1] = v2;
      candm[n5][w * 3 + 2] = v3;
    }
    __syncthreads();

    // ===== phase 3: 8 lanes/row x 32 dims; f64 re-eval of top-3-of-12 =====
    double lossW = 0.0;
    {
      float m1 = 3e38f, m2 = 3e38f, m3 = 3e38f;
#pragma unroll
      for (int cd = 0; cd < 12; ++cd) ins3(m1, m2, m3, candm[rowL][cd]);
      const int c1 = (int)(__builtin_bit_cast(uint, m1) & 1023u);
      const int c2 = (int)(__builtin_bit_cast(uint, m2) & 1023u);
      const int c3 = (int)(__builtin_bit_cast(uint, m3) & 1023u);

      const float* cbs = cb + (size_t)s * K_ * D_;
      const float* cr0 = cbs + (size_t)c1 * D_;
      const float* cr1 = cbs + (size_t)c2 * D_;
      const float* cr2 = cbs + (size_t)c3 * D_;
      double dd0 = 0.0, dd1 = 0.0, dd2 = 0.0;
#pragma unroll
      for (int cc = 0; cc < 4; ++cc) {
        const int blk = dq * 4 + cc;
        const int po = rowL * RST + swz(blk) * 8;
        const float4 h0 = *(const float4*)(resHi + po), h1 = *(const float4*)(resHi + po + 4);
        const double r64[8] = {(double)h0.x + lo[cc][0], (double)h0.y + lo[cc][1],
                               (double)h0.z + lo[cc][2], (double)h0.w + lo[cc][3],
                               (double)h1.x + lo[cc][4], (double)h1.y + lo[cc][5],
                               (double)h1.z + lo[cc][6], (double)h1.w + lo[cc][7]};
        const int go = blk * 8;
        const float4 a0 = *(const float4*)(cr0 + go), a1 = *(const float4*)(cr0 + go + 4);
        const float4 b0 = *(const float4*)(cr1 + go), b1 = *(const float4*)(cr1 + go + 4);
        const float4 g0 = *(const float4*)(cr2 + go), g1 = *(const float4*)(cr2 + go + 4);
        const float af[8] = {a0.x, a0.y, a0.z, a0.w, a1.x, a1.y, a1.z, a1.w};
        const float bf[8] = {b0.x, b0.y, b0.z, b0.w, b1.x, b1.y, b1.z, b1.w};
        const float gf[8] = {g0.x, g0.y, g0.z, g0.w, g1.x, g1.y, g1.z, g1.w};
#pragma unroll
        for (int j = 0; j < 8; ++j) {
          const double u = r64[j] - (double)af[j]; dd0 += u * u;
          const double v = r64[j] - (double)bf[j]; dd1 += v * v;
          const double g = r64[j] - (double)gf[j]; dd2 += g * g;
        }
      }
#pragma unroll
      for (int m = 1; m <= 4; m <<= 1) {
        dd0 += __shfl_xor(dd0, m); dd1 += __shfl_xor(dd1, m); dd2 += __shfl_xor(dd2, m);
      }
      int win = c1; double dwn = dd0;
      if (dd1 < dwn || (dd1 == dwn && c2 < win)) { win = c2; dwn = dd1; }
      if (dd2 < dwn || (dd2 == dwn && c3 < win)) { win = c3; dwn = dd2; }
      const float* crw = cbs + (size_t)win * D_;
#pragma unroll
      for (int cc = 0; cc < 4; ++cc) {
        const int blk = dq * 4 + cc;
        const int po = rowL * RST + swz(blk) * 8;
        const float4 h0 = *(const float4*)(resHi + po), h1 = *(const float4*)(resHi + po + 4);
        const int go = blk * 8;
        const float4 w0 = *(const float4*)(crw + go), w1 = *(const float4*)(crw + go + 4);
        const double n64[8] = {((double)h0.x + lo[cc][0]) - w0.x, ((double)h0.y + lo[cc][1]) - w0.y,
                               ((double)h0.z + lo[cc][2]) - w0.z, ((double)h0.w + lo[cc][3]) - w0.w,
                               ((double)h1.x + lo[cc][4]) - w1.x, ((double)h1.y + lo[cc][5]) - w1.y,
                               ((double)h1.z + lo[cc][6]) - w1.z, ((double)h1.w + lo[cc][7]) - w1.w};
        if (s < NQ_ - 1) {
          float hi[8];
#pragma unroll
          for (int j = 0; j < 8; ++j) {
            hi[j] = (float)n64[j];
            lo[cc][j] = (float)(n64[j] - (double)hi[j]);
          }
          *(float4*)(resHi + po)     = make_float4(hi[0], hi[1], hi[2], hi[3]);
          *(float4*)(resHi + po + 4) = make_float4(hi[4], hi[5], hi[6], hi[7]);
        } else {
          const float* xp = xT + (row0 + rowL) * D_ + go;
          const float4 x0 = *(const float4*)xp, x1 = *(const float4*)(xp + 4);
          float o[8];
          o[0] = (float)((double)x0.x - n64[0]); o[1] = (float)((double)x0.y - n64[1]);
          o[2] = (float)((double)x0.z - n64[2]); o[3] = (float)((double)x0.w - n64[3]);
          o[4] = (float)((double)x1.x - n64[4]); o[5] = (float)((double)x1.y - n64[5]);
          o[6] = (float)((double)x1.z - n64[6]); o[7] = (float)((double)x1.w - n64[7]);
          float* od = out + (row0 + rowL) * D_ + go;
          *(float4*)od       = make_float4(o[0], o[1], o[2], o[3]);
          *(float4*)(od + 4) = make_float4(o[4], o[5], o[6], o[7]);
        }
      }
      if (dq == 0) {
        out[IDX_OFF + (size_t)s * (B_ * T_) + row0 + rowL] = (float)win;
        lossW = dwn;
      }
    }
    // lossW nonzero only on lanes with dq==0 (l % 8 == 0): masks 8/16/32 suffice
#pragma unroll
    for (int m = 8; m <= 32; m <<= 1) lossW += __shfl_xor(lossW, m);
    if (l == 0) atomicAdd(&lossbuf[s], lossW);
    __syncthreads();
  }
}

__global__ void rvq_loss(const double* __restrict__ lossbuf, float* __restrict__ out) {
  const int s = threadIdx.x;
  if (s < NQ_) out[LOSS_OFF + s] = (float)(2.0 * lossbuf[s] / (double)((size_t)B_ * T_ * D_));
}

extern "C" void kernel_launch(void* const* d_in, const int* in_sizes, int n_in,
                              void* d_out, int out_size, void* d_ws, size_t ws_size,
                              hipStream_t stream) {
  const float* x  = (const float*)d_in[0];   // [B, D, T] f32
  const float* cb = (const float*)d_in[1];   // [NQ, K, D] f32
  float* out = (float*)d_out;
  char* ws = (char*)d_ws;
  float*  xTp   = (float*)(ws + XT_OFF);
  ushort* cb16p = (ushort*)(ws + CB16_OFF);
  float*  cnp   = (float*)(ws + CN_OFF);
  double* lbp   = (double*)(ws + LB_OFF);

  hipMemsetAsync(ws + LB_OFF, 0, NQ_ * sizeof(double), stream);
  prep_xT<<<2048, 256, 0, stream>>>(x, xTp);
  prep_cb16<<<2048, 256, 0, stream>>>(cb, cb16p, cnp);
  rvq_main<<<1024, 256, 0, stream>>>(cb, xTp, cb16p, cnp, out, lbp);
  rvq_loss<<<1, 64, 0, stream>>>(lbp, out);
}